// Round 1
// baseline (107.035 us; speedup 1.0000x reference)
//
#include <hip/hip_runtime.h>

// Problem constants
#define N_FILTERS 1024
#define B_TOTAL   1024
#define IMG       64          // H = W = 64
#define LDS_ROWS  70          // padded image rows (64 + 2*3)
#define LDS_STRIDE 76         // row stride in floats: mult of 4 (16B-aligned interior), 76%32=12 bank skew
// padded image col pc stored at LDS col (pc+1) so interior (pc=3..66) starts at col 4 -> float4 aligned

// ---------------- prep: transpose weight [1024][25] -> Wt [25][1024] ----------------
__global__ void prep_wt_kernel(const float* __restrict__ W, float* __restrict__ Wt) {
    int idx = blockIdx.x * 256 + threadIdx.x;        // idx = k*1024 + f, lanes -> consecutive f
    if (idx < 25 * N_FILTERS) {
        int k = idx >> 10;
        int f = idx & (N_FILTERS - 1);
        Wt[idx] = W[f * 25 + k];
    }
}

// ---------------- main: one block per batch image ----------------
__global__ __launch_bounds__(256, 4) void filters_main(
    const float* __restrict__ X,      // [B,1,64,64]
    const float* __restrict__ Wg,     // [F,1,5,5]   (fallback path)
    const float* __restrict__ Wt,     // [25,F]      (transposed)
    const float* __restrict__ bias,   // [F]
    const int*   __restrict__ pos,    // [F,2]
    float*       __restrict__ out,    // [B, F*4]
    int use_wt)
{
    __shared__ float L[LDS_ROWS * LDS_STRIDE];
    const int b = blockIdx.x;
    const int t = threadIdx.x;

    // zero the padded image (borders must be 0)
    for (int idx = t; idx < LDS_ROWS * LDS_STRIDE; idx += 256) L[idx] = 0.0f;
    __syncthreads();

    // stage interior 64x64, float4-coalesced; LDS addr (r+3)*76 + 4 + 4*c4 is 16B aligned
    const float4* X4 = (const float4*)(X + (size_t)b * (IMG * IMG));
    for (int q = t; q < (IMG * IMG / 4); q += 256) {
        int r  = q >> 4;          // image row 0..63
        int c4 = q & 15;          // float4 index within row
        float4 v = X4[q];
        *(float4*)&L[(r + 3) * LDS_STRIDE + 4 + (c4 << 2)] = v;
    }
    __syncthreads();

    // 4 filters per thread; lanes cover consecutive f -> coalesced Wt/bias/out
    #pragma unroll 1
    for (int chunk = 0; chunk < 4; ++chunk) {
        const int f = t + (chunk << 8);
        const int i = pos[2 * f];       // top-left row in padded image, 0..59
        const int j = pos[2 * f + 1];   // top-left col in padded image, 0..59

        float w[25];
        if (use_wt) {
            #pragma unroll
            for (int k = 0; k < 25; ++k) w[k] = Wt[k * N_FILTERS + f];
        } else {
            #pragma unroll
            for (int k = 0; k < 25; ++k) w[k] = Wg[f * 25 + k];
        }

        // conv outputs rows/cols 0..5 only (pool floor mode discards row/col 6)
        float acc[6][6];
        #pragma unroll
        for (int y = 0; y < 6; ++y)
            #pragma unroll
            for (int x = 0; x < 6; ++x) acc[y][x] = 0.0f;

        // window rows 0..9 and cols 0..9 are the only ones consumed
        const float* Lb = &L[i * LDS_STRIDE + j + 1];
        #pragma unroll
        for (int wr = 0; wr < 10; ++wr) {
            float in[10];
            #pragma unroll
            for (int wc = 0; wc < 10; ++wc) in[wc] = Lb[wr * LDS_STRIDE + wc];
            // conv row y uses window rows y..y+4  =>  y in [max(0,wr-4), min(5,wr)]
            #pragma unroll
            for (int y = 0; y < 6; ++y) {
                if (y >= ((wr > 4) ? (wr - 4) : 0) && y <= ((wr < 5) ? wr : 5)) {
                    const int r = wr - y;
                    #pragma unroll
                    for (int x = 0; x < 6; ++x) {
                        #pragma unroll
                        for (int c = 0; c < 5; ++c)
                            acc[y][x] = fmaf(w[r * 5 + c], in[x + c], acc[y][x]);
                    }
                }
            }
        }

        // 3x3 maxpool over the 6x6 grid -> 2x2; bias added after max (max(v)+b == max(v+b))
        const float bv = bias[f];
        float p[2][2];
        #pragma unroll
        for (int py = 0; py < 2; ++py) {
            #pragma unroll
            for (int px = 0; px < 2; ++px) {
                float m = acc[3 * py][3 * px];
                #pragma unroll
                for (int dy = 0; dy < 3; ++dy)
                    #pragma unroll
                    for (int dx = 0; dx < 3; ++dx)
                        m = fmaxf(m, acc[3 * py + dy][3 * px + dx]);
                p[py][px] = m + bv;
            }
        }

        float4 o;
        o.x = p[0][0]; o.y = p[0][1]; o.z = p[1][0]; o.w = p[1][1];
        *(float4*)&out[(size_t)b * (N_FILTERS * 4) + (f << 2)] = o;
    }
}

extern "C" void kernel_launch(void* const* d_in, const int* in_sizes, int n_in,
                              void* d_out, int out_size, void* d_ws, size_t ws_size,
                              hipStream_t stream) {
    const float* X    = (const float*)d_in[0];
    const float* W    = (const float*)d_in[1];
    const float* bias = (const float*)d_in[2];
    const int*   pos  = (const int*)d_in[3];
    float* out = (float*)d_out;
    float* Wt  = (float*)d_ws;

    const int use_wt = (ws_size >= (size_t)(25 * N_FILTERS * sizeof(float))) ? 1 : 0;
    if (use_wt) {
        prep_wt_kernel<<<(25 * N_FILTERS + 255) / 256, 256, 0, stream>>>(W, Wt);
    }
    filters_main<<<B_TOTAL, 256, 0, stream>>>(X, W, Wt, bias, pos, out, use_wt);
}

// Round 2
// 102.795 us; speedup vs baseline: 1.0412x; 1.0412x over previous
//
#include <hip/hip_runtime.h>

// Problem constants
#define N_FILTERS 1024
#define B_TOTAL   1024
#define IMG       64          // H = W = 64
#define LDS_ROWS  70          // padded image rows (64 + 2*3)
#define LDS_STRIDE 76         // row stride in floats: mult of 4 (16B-aligned interior), 76%32=12 bank skew
// padded image col pc stored at LDS col (pc+1) so interior (pc=3..66) starts at col 4 -> float4 aligned
// cols actually read: 1..70 (window cols j+1 .. j+10, j in [0,59]); cols 0 and 71..75 never read

// ---------------- prep: transpose weight [1024][25] -> Wt [25][1024] ----------------
__global__ void prep_wt_kernel(const float* __restrict__ W, float* __restrict__ Wt) {
    int idx = blockIdx.x * 256 + threadIdx.x;        // idx = k*1024 + f, lanes -> consecutive f
    if (idx < 25 * N_FILTERS) {
        int k = idx >> 10;
        int f = idx & (N_FILTERS - 1);
        Wt[idx] = W[f * 25 + k];
    }
}

// ---------------- main: one block per batch image ----------------
// __launch_bounds__(256, 2): 256-VGPR budget. Live set is >=71 floats
// (acc 36 + w 25 + in 10) + temps; the old (256,4)=128-VGPR cap risked spills.
__global__ __launch_bounds__(256, 2) void filters_main(
    const float* __restrict__ X,      // [B,1,64,64]
    const float* __restrict__ Wt,     // [25,F]      (transposed)
    const float* __restrict__ bias,   // [F]
    const int*   __restrict__ pos,    // [F,2]
    float*       __restrict__ out)    // [B, F*4]
{
    __shared__ float L[LDS_ROWS * LDS_STRIDE];
    const int b = blockIdx.x;
    const int t = threadIdx.x;

    // Border-only zeroing (840 elements instead of 5320):
    //  - full rows 0..2 and 67..69 (6 rows x 76)
    //  - side pads cols 1..3 and 68..70 for rows 3..66
    {
        // 6 full rows * 76 = 456 elements
        for (int idx = t; idx < 6 * LDS_STRIDE; idx += 256) {
            int r = idx / LDS_STRIDE;          // 0..5
            int c = idx - r * LDS_STRIDE;
            int row = (r < 3) ? r : (64 + r);  // 0,1,2, 67,68,69
            L[row * LDS_STRIDE + c] = 0.0f;
        }
        // side pads: 64 rows x 6 cols = 384 elements
        for (int idx = t; idx < 64 * 6; idx += 256) {
            int r = idx / 6;                   // 0..63 -> rows 3..66
            int c = idx - r * 6;               // 0..5
            int col = (c < 3) ? (1 + c) : (65 + c);   // 1,2,3, 68,69,70
            L[(r + 3) * LDS_STRIDE + col] = 0.0f;
        }
    }
    __syncthreads();

    // stage interior 64x64, float4-coalesced; LDS addr (r+3)*76 + 4 + 4*c4 is 16B aligned
    const float4* X4 = (const float4*)(X + (size_t)b * (IMG * IMG));
    for (int q = t; q < (IMG * IMG / 4); q += 256) {
        int r  = q >> 4;          // image row 0..63
        int c4 = q & 15;          // float4 index within row
        float4 v = X4[q];
        *(float4*)&L[(r + 3) * LDS_STRIDE + 4 + (c4 << 2)] = v;
    }
    __syncthreads();

    // 4 filters per thread; lanes cover consecutive f -> coalesced Wt/bias/out
    #pragma unroll 1
    for (int chunk = 0; chunk < 4; ++chunk) {
        const int f = t + (chunk << 8);
        const int i = pos[2 * f];       // top-left row in padded image, 0..59
        const int j = pos[2 * f + 1];   // top-left col in padded image, 0..59

        float w[25];
        #pragma unroll
        for (int k = 0; k < 25; ++k) w[k] = Wt[k * N_FILTERS + f];

        // conv outputs rows/cols 0..5 only (pool floor mode discards row/col 6)
        float acc[6][6];
        #pragma unroll
        for (int y = 0; y < 6; ++y)
            #pragma unroll
            for (int x = 0; x < 6; ++x) acc[y][x] = 0.0f;

        // window rows 0..9 and cols 0..9 are the only ones consumed
        const float* Lb = &L[i * LDS_STRIDE + j + 1];
        #pragma unroll
        for (int wr = 0; wr < 10; ++wr) {
            float in[10];
            #pragma unroll
            for (int wc = 0; wc < 10; ++wc) in[wc] = Lb[wr * LDS_STRIDE + wc];
            // conv row y uses window rows y..y+4  =>  y in [max(0,wr-4), min(5,wr)]
            #pragma unroll
            for (int y = 0; y < 6; ++y) {
                if (y >= ((wr > 4) ? (wr - 4) : 0) && y <= ((wr < 5) ? wr : 5)) {
                    const int r = wr - y;
                    #pragma unroll
                    for (int x = 0; x < 6; ++x) {
                        #pragma unroll
                        for (int c = 0; c < 5; ++c)
                            acc[y][x] = fmaf(w[r * 5 + c], in[x + c], acc[y][x]);
                    }
                }
            }
        }

        // 3x3 maxpool over the 6x6 grid -> 2x2; bias added after max (max(v)+b == max(v+b))
        const float bv = bias[f];
        float p[2][2];
        #pragma unroll
        for (int py = 0; py < 2; ++py) {
            #pragma unroll
            for (int px = 0; px < 2; ++px) {
                float m = acc[3 * py][3 * px];
                #pragma unroll
                for (int dy = 0; dy < 3; ++dy)
                    #pragma unroll
                    for (int dx = 0; dx < 3; ++dx)
                        m = fmaxf(m, acc[3 * py + dy][3 * px + dx]);
                p[py][px] = m + bv;
            }
        }

        float4 o;
        o.x = p[0][0]; o.y = p[0][1]; o.z = p[1][0]; o.w = p[1][1];
        *(float4*)&out[(size_t)b * (N_FILTERS * 4) + (f << 2)] = o;
    }
}

extern "C" void kernel_launch(void* const* d_in, const int* in_sizes, int n_in,
                              void* d_out, int out_size, void* d_ws, size_t ws_size,
                              hipStream_t stream) {
    const float* X    = (const float*)d_in[0];
    const float* W    = (const float*)d_in[1];
    const float* bias = (const float*)d_in[2];
    const int*   pos  = (const int*)d_in[3];
    float* out = (float*)d_out;
    float* Wt  = (float*)d_ws;   // 25*1024 floats = 100 KB, ws is plenty

    prep_wt_kernel<<<(25 * N_FILTERS + 255) / 256, 256, 0, stream>>>(W, Wt);
    filters_main<<<B_TOTAL, 256, 0, stream>>>(X, Wt, bias, pos, out);
}